// Round 1
// baseline (423.510 us; speedup 1.0000x reference)
//
#include <hip/hip_runtime.h>
#include <hip/hip_bf16.h>

// Static problem shape
// B=8, C=256, CQ=8, H=W=128, scale=4, Hd=Wd=32, N=1024

#define NB 8
#define NC 256
#define NCQ 8
#define NH 128
#define NW 128
#define ND 32
#define NN 1024   // ND*ND

// ---------------- ws layout (floats) ----------------
// xf    : [B][C][N]      @ 0          size 2097152
// qT    : [B][N][8]      @ 2097152    size 65536
// kT    : [B][N][8]      @ 2162688    size 65536
// stats : [B][N] float2  @ 2228224    size 16384 floats
// v     : [B][C][N]      @ 2244608    size 2097152
// outs  : [B][C][N]      @ 4341760    size 2097152
#define OFF_XF    0
#define OFF_QT    2097152
#define OFF_KT    2162688
#define OFF_STATS 2228224
#define OFF_V     2244608
#define OFF_OUTS  4341760

// ---------------------------------------------------------------------------
// 1) 4x4 average pool: x[B,C,128,128] -> xf[B,C,1024]
__global__ __launch_bounds__(256) void pool_kernel(const float* __restrict__ x,
                                                   float* __restrict__ xf) {
    int idx = blockIdx.x * 256 + threadIdx.x;      // 0..2097151
    int n = idx & 1023;
    int c = (idx >> 10) & 255;
    int b = idx >> 18;
    int hi = n >> 5, wi = n & 31;
    const float* p = x + ((size_t)(b * 256 + c) * 128 + hi * 4) * 128 + wi * 4;
    float s = 0.f;
#pragma unroll
    for (int r = 0; r < 4; ++r) {
        float4 v4 = *(const float4*)(p + r * 128);
        s += v4.x + v4.y + v4.z + v4.w;
    }
    xf[idx] = s * 0.0625f;
}

// ---------------------------------------------------------------------------
// 2) q,k projections -> qT[B][N][8], kT[B][N][8] (transposed for 32B/row reads)
__global__ __launch_bounds__(256) void qk_kernel(const float* __restrict__ xf,
                                                 const float* __restrict__ Wq,
                                                 const float* __restrict__ bq,
                                                 const float* __restrict__ Wk,
                                                 const float* __restrict__ bk,
                                                 float* __restrict__ qT,
                                                 float* __restrict__ kT) {
    __shared__ float sW[4096 + 16];
    int t = threadIdx.x;
    for (int i = t; i < 2048; i += 256) {
        sW[i] = Wq[i];
        sW[2048 + i] = Wk[i];
    }
    if (t < 8) { sW[4096 + t] = bq[t]; sW[4104 + t] = bk[t]; }
    __syncthreads();

    int b = blockIdx.x >> 2;
    int n = ((blockIdx.x & 3) << 8) | t;
    float aq[8] = {0,0,0,0,0,0,0,0};
    float ak[8] = {0,0,0,0,0,0,0,0};
    const float* xp = xf + (size_t)b * (256 * 1024) + n;
    for (int c = 0; c < 256; ++c) {
        float xv = xp[(size_t)c * 1024];
#pragma unroll
        for (int j = 0; j < 8; ++j) {
            aq[j] = fmaf(sW[j * 256 + c], xv, aq[j]);
            ak[j] = fmaf(sW[2048 + j * 256 + c], xv, ak[j]);
        }
    }
    float* qo = qT + ((size_t)b * 1024 + n) * 8;
    float* ko = kT + ((size_t)b * 1024 + n) * 8;
#pragma unroll
    for (int j = 0; j < 8; ++j) {
        qo[j] = aq[j] + sW[4096 + j];
        ko[j] = ak[j] + sW[4104 + j];
    }
}

// ---------------------------------------------------------------------------
// 3) v projection: v[b,o,n] = sum_c Wv[o,c]*xf[b,c,n] + bv[o]
//    64x64 tile, BK=32, 4x4 per thread. grid = 8*4*16 = 512 blocks
__global__ __launch_bounds__(256) void vgemm_kernel(const float* __restrict__ xf,
                                                    const float* __restrict__ Wv,
                                                    const float* __restrict__ bv,
                                                    float* __restrict__ v) {
    int bid = blockIdx.x;
    int b = bid >> 6;
    int ot0 = ((bid >> 4) & 3) * 64;
    int nt0 = (bid & 15) * 64;
    __shared__ float WsT[32][64];  // [ck][o]
    __shared__ float Xs[32][64];   // [ck][n]
    int t = threadIdx.x;
    int to4 = (t >> 4) * 4, tn4 = (t & 15) * 4;
    float acc[4][4] = {};

    for (int c0 = 0; c0 < 256; c0 += 32) {
        {   // stage Wv tile (transposed)
            int o = t >> 2, ck0 = (t & 3) * 8;
            const float* wp = Wv + (size_t)(ot0 + o) * 256 + c0 + ck0;
            float4 a = *(const float4*)wp;
            float4 bb = *(const float4*)(wp + 4);
            WsT[ck0 + 0][o] = a.x;  WsT[ck0 + 1][o] = a.y;
            WsT[ck0 + 2][o] = a.z;  WsT[ck0 + 3][o] = a.w;
            WsT[ck0 + 4][o] = bb.x; WsT[ck0 + 5][o] = bb.y;
            WsT[ck0 + 6][o] = bb.z; WsT[ck0 + 7][o] = bb.w;
        }
        {   // stage xf tile (natural orientation)
            int c = t >> 3, nch = (t & 7) * 8;
            const float* xp = xf + (size_t)(b * 256 + c0 + c) * 1024 + nt0 + nch;
            *(float4*)&Xs[c][nch] = *(const float4*)xp;
            *(float4*)&Xs[c][nch + 4] = *(const float4*)(xp + 4);
        }
        __syncthreads();
#pragma unroll
        for (int ck = 0; ck < 32; ++ck) {
            float4 wv = *(float4*)&WsT[ck][to4];
            float4 xv = *(float4*)&Xs[ck][tn4];
            float wr[4] = {wv.x, wv.y, wv.z, wv.w};
            float xr[4] = {xv.x, xv.y, xv.z, xv.w};
#pragma unroll
            for (int i = 0; i < 4; ++i)
#pragma unroll
                for (int j = 0; j < 4; ++j)
                    acc[i][j] = fmaf(wr[i], xr[j], acc[i][j]);
        }
        __syncthreads();
    }
#pragma unroll
    for (int i = 0; i < 4; ++i) {
        float bias = bv[ot0 + to4 + i];
        float4 r;
        r.x = acc[i][0] + bias; r.y = acc[i][1] + bias;
        r.z = acc[i][2] + bias; r.w = acc[i][3] + bias;
        *(float4*)&v[(size_t)(b * 256 + ot0 + to4 + i) * 1024 + nt0 + tn4] = r;
    }
}

// ---------------------------------------------------------------------------
// 4) softmax row stats: for each (b,m): M = max_n q.k, L = sum exp(s-M)
__global__ __launch_bounds__(256) void stats_kernel(const float* __restrict__ qT,
                                                    const float* __restrict__ kT,
                                                    float2* __restrict__ stats) {
    __shared__ float ks[8192];     // kT[b] : 1024 x 8
    int t = threadIdx.x;
    int b = blockIdx.x >> 8;
    int mg = blockIdx.x & 255;
    const float* kp = kT + (size_t)b * 8192;
    for (int i = t * 4; i < 8192; i += 1024)
        *(float4*)&ks[i] = *(const float4*)&kp[i];
    __syncthreads();

    int w = t >> 6, ln = t & 63;
    int m = mg * 4 + w;
    const float* qp = qT + ((size_t)b * 1024 + m) * 8;
    float4 q0 = *(const float4*)qp, q1 = *(const float4*)(qp + 4);

    float s[16];
    float mx = -1e30f;
#pragma unroll
    for (int i = 0; i < 16; ++i) {
        int n = ln + i * 64;
        const float* kk = &ks[n * 8];
        float4 k0 = *(const float4*)kk, k1 = *(const float4*)(kk + 4);
        float d = q0.x * k0.x + q0.y * k0.y + q0.z * k0.z + q0.w * k0.w +
                  q1.x * k1.x + q1.y * k1.y + q1.z * k1.z + q1.w * k1.w;
        s[i] = d;
        mx = fmaxf(mx, d);
    }
#pragma unroll
    for (int off = 32; off; off >>= 1) mx = fmaxf(mx, __shfl_xor(mx, off, 64));
    float sum = 0.f;
#pragma unroll
    for (int i = 0; i < 16; ++i) sum += __expf(s[i] - mx);
#pragma unroll
    for (int off = 32; off; off >>= 1) sum += __shfl_xor(sum, off, 64);
    if (ln == 0) stats[(size_t)b * 1024 + m] = make_float2(mx, 1.0f / sum);
}

// ---------------------------------------------------------------------------
// 5) fused PV GEMM: outs[b,c,m] = sum_n v[b,c,n] * exp(q_m.k_n - M_m)*invL_m
//    P tile recomputed on the fly (attn never materialized).
__global__ __launch_bounds__(256) void pv_kernel(const float* __restrict__ v,
                                                 const float* __restrict__ qT,
                                                 const float* __restrict__ kT,
                                                 const float2* __restrict__ stats,
                                                 float* __restrict__ outs) {
    int bid = blockIdx.x;
    int b = bid >> 6;
    int ct0 = ((bid >> 4) & 3) * 64;
    int mt0 = (bid & 15) * 64;
    __shared__ float vsT[32][64];   // [n][c]
    __shared__ float psT[32][64];   // [n][m]
    __shared__ float qs[64][8];
    __shared__ float sM[64], sIL[64];
    int t = threadIdx.x;

    {   // prologue: q tile + stats
        const float* qp = qT + ((size_t)b * 1024 + mt0) * 8;
        if (t < 128) ((float4*)&qs[0][0])[t] = ((const float4*)qp)[t];
        if (t < 64) {
            float2 st = stats[(size_t)b * 1024 + mt0 + t];
            sM[t] = st.x; sIL[t] = st.y;
        }
    }
    __syncthreads();

    int tm4 = (t & 15) * 4, tc4 = (t >> 4) * 4;
    float acc[4][4] = {};

    for (int n0 = 0; n0 < 1024; n0 += 32) {
        __syncthreads();   // protect prev-iter LDS reads
        {   // stage v tile transposed
            int c = t >> 2, nch = (t & 3) * 8;
            const float* vp = v + (size_t)(b * 256 + ct0 + c) * 1024 + n0 + nch;
            float4 a = *(const float4*)vp;
            float4 bb = *(const float4*)(vp + 4);
            vsT[nch + 0][c] = a.x;  vsT[nch + 1][c] = a.y;
            vsT[nch + 2][c] = a.z;  vsT[nch + 3][c] = a.w;
            vsT[nch + 4][c] = bb.x; vsT[nch + 5][c] = bb.y;
            vsT[nch + 6][c] = bb.z; vsT[nch + 7][c] = bb.w;
        }
        {   // compute P tile: thread -> n = t&31, m0 = (t>>5)*8
            int n = t & 31, m0 = (t >> 5) * 8;
            const float* kp = kT + ((size_t)b * 1024 + n0 + n) * 8;
            float4 k0 = *(const float4*)kp, k1 = *(const float4*)(kp + 4);
            float pv[8];
#pragma unroll
            for (int j = 0; j < 8; ++j) {
                const float* qv = &qs[m0 + j][0];
                float d = qv[0] * k0.x + qv[1] * k0.y + qv[2] * k0.z + qv[3] * k0.w +
                          qv[4] * k1.x + qv[5] * k1.y + qv[6] * k1.z + qv[7] * k1.w;
                pv[j] = __expf(d - sM[m0 + j]) * sIL[m0 + j];
            }
            *(float4*)&psT[n][m0]     = make_float4(pv[0], pv[1], pv[2], pv[3]);
            *(float4*)&psT[n][m0 + 4] = make_float4(pv[4], pv[5], pv[6], pv[7]);
        }
        __syncthreads();
#pragma unroll
        for (int n = 0; n < 32; ++n) {
            float4 vv = *(float4*)&vsT[n][tc4];
            float4 pp = *(float4*)&psT[n][tm4];
            float vr[4] = {vv.x, vv.y, vv.z, vv.w};
            float pr[4] = {pp.x, pp.y, pp.z, pp.w};
#pragma unroll
            for (int i = 0; i < 4; ++i)
#pragma unroll
                for (int j = 0; j < 4; ++j)
                    acc[i][j] = fmaf(vr[i], pr[j], acc[i][j]);
        }
    }
#pragma unroll
    for (int i = 0; i < 4; ++i) {
        float4 r;
        r.x = acc[i][0]; r.y = acc[i][1]; r.z = acc[i][2]; r.w = acc[i][3];
        *(float4*)&outs[(size_t)(b * 256 + ct0 + tc4 + i) * 1024 + mt0 + tm4] = r;
    }
}

// ---------------------------------------------------------------------------
// 6) bilinear 4x upsample (half-pixel, edge-clamped == jax renormalized) +
//    residual: out = gamma*up(outs) + x.   One block per (b,c) plane.
__global__ __launch_bounds__(256) void up_kernel(const float* __restrict__ outs,
                                                 const float* __restrict__ x,
                                                 const float* __restrict__ gamma,
                                                 float* __restrict__ out) {
    int bc = blockIdx.x;   // 0..2047
    __shared__ float P[32][33];
    int t = threadIdx.x;
    const float* sp = outs + (size_t)bc * 1024;
    for (int i = t; i < 1024; i += 256) P[i >> 5][i & 31] = sp[i];
    float g = gamma[0];
    __syncthreads();

    const float* xp = x + (size_t)bc * 16384;
    float* op = out + (size_t)bc * 16384;
#pragma unroll 1
    for (int it = 0; it < 16; ++it) {
        int pix = it * 256 + t;        // float4 index 0..4095
        int h = pix >> 5;              // row
        int wq = pix & 31;             // horizontal quad index; k = w&3
        int hq = h >> 2, r = h & 3;
        int i0 = hq + ((r < 2) ? -1 : 0);
        float fh = (r < 2) ? (0.625f + 0.25f * r) : (0.25f * r - 0.375f);
        int ha = i0 < 0 ? 0 : i0;
        int hb = (i0 + 1) > 31 ? 31 : (i0 + 1);
        float4 xv = *(const float4*)(xp + h * 128 + wq * 4);
        float res[4];
#pragma unroll
        for (int k = 0; k < 4; ++k) {
            int j0 = wq + ((k < 2) ? -1 : 0);
            float fw = (k < 2) ? (0.625f + 0.25f * k) : (0.25f * k - 0.375f);
            int wa = j0 < 0 ? 0 : j0;
            int wb = (j0 + 1) > 31 ? 31 : (j0 + 1);
            float ca = (1.f - fh) * P[ha][wa] + fh * P[hb][wa];
            float cb = (1.f - fh) * P[ha][wb] + fh * P[hb][wb];
            res[k] = (1.f - fw) * ca + fw * cb;
        }
        float4 o;
        o.x = fmaf(g, res[0], xv.x);
        o.y = fmaf(g, res[1], xv.y);
        o.z = fmaf(g, res[2], xv.z);
        o.w = fmaf(g, res[3], xv.w);
        *(float4*)(op + h * 128 + wq * 4) = o;
    }
}

// ---------------------------------------------------------------------------
extern "C" void kernel_launch(void* const* d_in, const int* in_sizes, int n_in,
                              void* d_out, int out_size, void* d_ws, size_t ws_size,
                              hipStream_t stream) {
    const float* x     = (const float*)d_in[0];
    const float* Wq    = (const float*)d_in[1];
    const float* bq    = (const float*)d_in[2];
    const float* Wk    = (const float*)d_in[3];
    const float* bk    = (const float*)d_in[4];
    const float* Wv    = (const float*)d_in[5];
    const float* bv    = (const float*)d_in[6];
    const float* gamma = (const float*)d_in[7];
    float* out = (float*)d_out;
    float* ws  = (float*)d_ws;

    float* xf    = ws + OFF_XF;
    float* qT    = ws + OFF_QT;
    float* kT    = ws + OFF_KT;
    float2* stats = (float2*)(ws + OFF_STATS);
    float* v     = ws + OFF_V;
    float* outs  = ws + OFF_OUTS;

    pool_kernel<<<8192, 256, 0, stream>>>(x, xf);
    qk_kernel<<<32, 256, 0, stream>>>(xf, Wq, bq, Wk, bk, qT, kT);
    vgemm_kernel<<<512, 256, 0, stream>>>(xf, Wv, bv, v);
    stats_kernel<<<2048, 256, 0, stream>>>(qT, kT, stats);
    pv_kernel<<<512, 256, 0, stream>>>(v, qT, kT, stats, outs);
    up_kernel<<<2048, 256, 0, stream>>>(outs, x, gamma, out);
}

// Round 2
// 346.719 us; speedup vs baseline: 1.2215x; 1.2215x over previous
//
#include <hip/hip_runtime.h>
#include <hip/hip_bf16.h>

// Static problem shape: B=8, C=256, CQ=8, H=W=128, scale=4, Hd=Wd=32, N=1024

typedef short bf16x8 __attribute__((ext_vector_type(8)));
typedef float f32x4 __attribute__((ext_vector_type(4)));
typedef unsigned short ushort_t;

// fp32 -> bf16 round-to-nearest-even (bit trick)
__device__ __forceinline__ ushort_t f2bf(float f) {
    union { float f; unsigned u; } x{f};
    unsigned r = x.u + 0x7FFF + ((x.u >> 16) & 1);
    return (ushort_t)(r >> 16);
}
__device__ __forceinline__ float bf2f(ushort_t u) {
    return __uint_as_float(((unsigned)u) << 16);
}

#define GLOAD_LDS16(gp, lp)                                                          \
    __builtin_amdgcn_global_load_lds((const __attribute__((address_space(1))) void*)(gp), \
                                     (__attribute__((address_space(3))) void*)(lp), 16, 0, 0)

// ---------------- ws layout (bytes) ----------------
// P    bf16 [8][1024][1024] @ 0         (16 MiB)  -- overlays xf (dead after vgemm)
// xf   f32  [8][256][1024]  @ 0         (8 MiB, phase 1 only)
// qT   f32  [8][1024][8]    @ 16777216  (256 KB)
// kT   f32  [8][1024][8]    @ 17039360  (256 KB)
// v    bf16 [8][256][1024]  @ 17301504  (4 MiB)
// outs bf16 [8][256][1024]  @ 21495808  (4 MiB)
// total 24.5 MiB (round-1 used 25.8 MiB OK)

// ---------------------------------------------------------------------------
// 1) 4x4 average pool: x[B,C,128,128] -> xf[B,C,1024] (fp32)
__global__ __launch_bounds__(256) void pool_kernel(const float* __restrict__ x,
                                                   float* __restrict__ xf) {
    int idx = blockIdx.x * 256 + threadIdx.x;      // 0..2097151
    int n = idx & 1023;
    int c = (idx >> 10) & 255;
    int b = idx >> 18;
    int hi = n >> 5, wi = n & 31;
    const float* p = x + ((size_t)(b * 256 + c) * 128 + hi * 4) * 128 + wi * 4;
    float s = 0.f;
#pragma unroll
    for (int r = 0; r < 4; ++r) {
        float4 v4 = *(const float4*)(p + r * 128);
        s += v4.x + v4.y + v4.z + v4.w;
    }
    xf[idx] = s * 0.0625f;
}

// ---------------------------------------------------------------------------
// 2) q,k projections -> qT[B][N][8], kT[B][N][8].
//    grid = 8*16 = 128 blocks; 256 thr = 64 n x 4 c-quarters; LDS reduce.
__global__ __launch_bounds__(256) void qk_kernel(const float* __restrict__ xf,
                                                 const float* __restrict__ Wq,
                                                 const float* __restrict__ bq,
                                                 const float* __restrict__ Wk,
                                                 const float* __restrict__ bk,
                                                 float* __restrict__ qT,
                                                 float* __restrict__ kT) {
    __shared__ float sW[4112];
    __shared__ float red[4352];     // [cq][64 n][17] padded
    int t = threadIdx.x;
    for (int i = t; i < 2048; i += 256) {
        sW[i] = Wq[i];
        sW[2048 + i] = Wk[i];
    }
    if (t < 8) { sW[4096 + t] = bq[t]; sW[4104 + t] = bk[t]; }
    __syncthreads();

    int b = blockIdx.x >> 4;
    int ng = blockIdx.x & 15;
    int nl = t & 63, cq = t >> 6;
    float a[16];
#pragma unroll
    for (int j = 0; j < 16; ++j) a[j] = 0.f;
    const float* xp = xf + (size_t)b * 262144 + ng * 64 + nl;
    for (int c = cq * 64; c < cq * 64 + 64; ++c) {
        float xv = xp[(size_t)c * 1024];
#pragma unroll
        for (int j = 0; j < 8; ++j) {
            a[j]     = fmaf(sW[j * 256 + c], xv, a[j]);
            a[8 + j] = fmaf(sW[2048 + j * 256 + c], xv, a[8 + j]);
        }
    }
    float* rp = &red[(cq * 64 + nl) * 17];
#pragma unroll
    for (int j = 0; j < 16; ++j) rp[j] = a[j];
    __syncthreads();
#pragma unroll
    for (int u = 0; u < 4; ++u) {
        int o = t * 4 + u;
        int n = o >> 4, j = o & 15;
        float s = red[(n) * 17 + j] + red[(64 + n) * 17 + j] +
                  red[(128 + n) * 17 + j] + red[(192 + n) * 17 + j] + sW[4096 + j];
        if (j < 8) qT[((size_t)b * 1024 + ng * 64 + n) * 8 + j] = s;
        else       kT[((size_t)b * 1024 + ng * 64 + n) * 8 + j - 8] = s;
    }
}

// ---------------------------------------------------------------------------
// 3) v projection (fp32 compute, bf16 out): v[b,o,n] = sum_c Wv[o,c]*xf[b,c,n]+bv[o]
__global__ __launch_bounds__(256) void vgemm_kernel(const float* __restrict__ xf,
                                                    const float* __restrict__ Wv,
                                                    const float* __restrict__ bv,
                                                    ushort_t* __restrict__ v) {
    int bid = blockIdx.x;
    int b = bid >> 6;
    int ot0 = ((bid >> 4) & 3) * 64;
    int nt0 = (bid & 15) * 64;
    __shared__ float WsT[32][64];  // [ck][o]
    __shared__ float Xs[32][64];   // [ck][n]
    int t = threadIdx.x;
    int to4 = (t >> 4) * 4, tn4 = (t & 15) * 4;
    float acc[4][4] = {};

    for (int c0 = 0; c0 < 256; c0 += 32) {
        {   // stage Wv tile (transposed)
            int o = t >> 2, ck0 = (t & 3) * 8;
            const float* wp = Wv + (size_t)(ot0 + o) * 256 + c0 + ck0;
            float4 aa = *(const float4*)wp;
            float4 bb = *(const float4*)(wp + 4);
            WsT[ck0 + 0][o] = aa.x;  WsT[ck0 + 1][o] = aa.y;
            WsT[ck0 + 2][o] = aa.z;  WsT[ck0 + 3][o] = aa.w;
            WsT[ck0 + 4][o] = bb.x; WsT[ck0 + 5][o] = bb.y;
            WsT[ck0 + 6][o] = bb.z; WsT[ck0 + 7][o] = bb.w;
        }
        {   // stage xf tile
            int c = t >> 3, nch = (t & 7) * 8;
            const float* xp = xf + (size_t)(b * 256 + c0 + c) * 1024 + nt0 + nch;
            *(float4*)&Xs[c][nch] = *(const float4*)xp;
            *(float4*)&Xs[c][nch + 4] = *(const float4*)(xp + 4);
        }
        __syncthreads();
#pragma unroll
        for (int ck = 0; ck < 32; ++ck) {
            float4 wv = *(float4*)&WsT[ck][to4];
            float4 xv = *(float4*)&Xs[ck][tn4];
            float wr[4] = {wv.x, wv.y, wv.z, wv.w};
            float xr[4] = {xv.x, xv.y, xv.z, xv.w};
#pragma unroll
            for (int i = 0; i < 4; ++i)
#pragma unroll
                for (int j = 0; j < 4; ++j)
                    acc[i][j] = fmaf(wr[i], xr[j], acc[i][j]);
        }
        __syncthreads();
    }
#pragma unroll
    for (int i = 0; i < 4; ++i) {
        float bias = bv[ot0 + to4 + i];
        ushort4 r;
        r.x = f2bf(acc[i][0] + bias); r.y = f2bf(acc[i][1] + bias);
        r.z = f2bf(acc[i][2] + bias); r.w = f2bf(acc[i][3] + bias);
        *(ushort4*)&v[(size_t)(b * 256 + ot0 + to4 + i) * 1024 + nt0 + tn4] = r;
    }
}

// ---------------------------------------------------------------------------
// 4) fused softmax stats + P matrix (bf16): P[b,m,n] = exp(q_m.k_n - M_m)/L_m
//    grid = 8*64 = 512 blocks; block handles 16 m rows (4 passes x 4 waves).
__global__ __launch_bounds__(256) void pmat_kernel(const float* __restrict__ qT,
                                                   const float* __restrict__ kT,
                                                   ushort_t* __restrict__ Pm) {
    __shared__ float ks[8192];     // kT[b] : 1024 x 8
    int t = threadIdx.x;
    int b = blockIdx.x >> 6;
    int mg = blockIdx.x & 63;
    const float* kp = kT + (size_t)b * 8192;
    for (int i = t * 4; i < 8192; i += 1024)
        *(float4*)&ks[i] = *(const float4*)&kp[i];
    __syncthreads();

    int w = t >> 6, ln = t & 63;
#pragma unroll 1
    for (int pass = 0; pass < 4; ++pass) {
        int m = mg * 16 + pass * 4 + w;
        const float* qp = qT + ((size_t)b * 1024 + m) * 8;
        float4 q0 = *(const float4*)qp, q1 = *(const float4*)(qp + 4);
        float s[16];
        float mx = -1e30f;
#pragma unroll
        for (int i = 0; i < 16; ++i) {
            const float* kk = &ks[(ln + i * 64) * 8];
            float4 k0 = *(const float4*)kk, k1 = *(const float4*)(kk + 4);
            float d = q0.x * k0.x + q0.y * k0.y + q0.z * k0.z + q0.w * k0.w +
                      q1.x * k1.x + q1.y * k1.y + q1.z * k1.z + q1.w * k1.w;
            s[i] = d;
            mx = fmaxf(mx, d);
        }
#pragma unroll
        for (int off = 32; off; off >>= 1) mx = fmaxf(mx, __shfl_xor(mx, off, 64));
        float sum = 0.f;
#pragma unroll
        for (int i = 0; i < 16; ++i) { s[i] = __expf(s[i] - mx); sum += s[i]; }
#pragma unroll
        for (int off = 32; off; off >>= 1) sum += __shfl_xor(sum, off, 64);
        float inv = 1.0f / sum;
        ushort_t* pp = Pm + ((size_t)b * 1024 + m) * 1024;
#pragma unroll
        for (int i = 0; i < 16; ++i) pp[ln + i * 64] = f2bf(s[i] * inv);
    }
}

// ---------------------------------------------------------------------------
// 5) PV GEMM, bf16 MFMA: outs[b,c,m] = sum_n v[b,c,n] * P[b,m,n]
//    64x64 output tile, BK=64, global_load_lds(16B) staging, m97 structure.
__global__ __launch_bounds__(256) void pv_mfma_kernel(const ushort_t* __restrict__ v,
                                                      const ushort_t* __restrict__ Pm,
                                                      ushort_t* __restrict__ outs) {
    int bid = blockIdx.x;
    int b = bid >> 6;
    int ct0 = ((bid >> 4) & 3) * 64;
    int mt0 = (bid & 15) * 64;
    __shared__ __align__(16) short vs[4096];   // [64 c][64 k] bf16, 128B rows
    __shared__ __align__(16) short ps[4096];   // [64 m][64 k] bf16
    int t = threadIdx.x;
    int w = t >> 6, ln = t & 63;
    int lrow = ln >> 3, lcol = ln & 7;         // staging: 8 rows x 128B per instr

    const char* vg = (const char*)(v + (size_t)(b * 256 + ct0) * 1024);
    const char* pg = (const char*)(Pm + (size_t)(b * 1024 + mt0) * 1024);

    f32x4 acc[4] = {};
    int fr = ln & 15, quad = ln >> 4;

    for (int n0 = 0; n0 < 1024; n0 += 64) {
        __syncthreads();   // protect prev-iter LDS reads
#pragma unroll
        for (int s = w; s < 8; s += 4) {       // segs w, w+4
            GLOAD_LDS16(vg + (size_t)(s * 8 + lrow) * 2048 + n0 * 2 + lcol * 16,
                        (char*)vs + s * 1024);
            GLOAD_LDS16(pg + (size_t)(s * 8 + lrow) * 2048 + n0 * 2 + lcol * 16,
                        (char*)ps + s * 1024);
        }
        __syncthreads();   // staged (compiler drains vmcnt before barrier)
        const short* va = vs + (w * 16 + fr) * 64;
#pragma unroll
        for (int kh = 0; kh < 2; ++kh) {
            bf16x8 af = *(const bf16x8*)(va + kh * 32 + quad * 8);
#pragma unroll
            for (int mt = 0; mt < 4; ++mt) {
                bf16x8 bfr = *(const bf16x8*)(ps + (mt * 16 + fr) * 64 + kh * 32 + quad * 8);
                acc[mt] = __builtin_amdgcn_mfma_f32_16x16x32_bf16(af, bfr, acc[mt], 0, 0, 0);
            }
        }
    }
    // epilogue: C/D layout col=lane&15 (m), row=quad*4+reg (c)
    ushort_t* og = outs + (size_t)(b * 256 + ct0 + w * 16) * 1024 + mt0;
#pragma unroll
    for (int mt = 0; mt < 4; ++mt) {
#pragma unroll
        for (int r = 0; r < 4; ++r) {
            int c = quad * 4 + r;
            og[(size_t)c * 1024 + mt * 16 + fr] = f2bf(acc[mt][r]);
        }
    }
}

// ---------------------------------------------------------------------------
// 6) bilinear 4x upsample + residual: out = gamma*up(outs) + x
__global__ __launch_bounds__(256) void up_kernel(const ushort_t* __restrict__ outs,
                                                 const float* __restrict__ x,
                                                 const float* __restrict__ gamma,
                                                 float* __restrict__ out) {
    int bc = blockIdx.x;   // 0..2047
    __shared__ float P[32][33];
    int t = threadIdx.x;
    const ushort_t* sp = outs + (size_t)bc * 1024;
    for (int i = t; i < 1024; i += 256) P[i >> 5][i & 31] = bf2f(sp[i]);
    float g = gamma[0];
    __syncthreads();

    const float* xp = x + (size_t)bc * 16384;
    float* op = out + (size_t)bc * 16384;
#pragma unroll 1
    for (int it = 0; it < 16; ++it) {
        int pix = it * 256 + t;        // float4 index 0..4095
        int h = pix >> 5;
        int wq = pix & 31;
        int hq = h >> 2, r = h & 3;
        int i0 = hq + ((r < 2) ? -1 : 0);
        float fh = (r < 2) ? (0.625f + 0.25f * r) : (0.25f * r - 0.375f);
        int ha = i0 < 0 ? 0 : i0;
        int hb = (i0 + 1) > 31 ? 31 : (i0 + 1);
        float4 xv = *(const float4*)(xp + h * 128 + wq * 4);
        float res[4];
#pragma unroll
        for (int k = 0; k < 4; ++k) {
            int j0 = wq + ((k < 2) ? -1 : 0);
            float fw = (k < 2) ? (0.625f + 0.25f * k) : (0.25f * k - 0.375f);
            int wa = j0 < 0 ? 0 : j0;
            int wb = (j0 + 1) > 31 ? 31 : (j0 + 1);
            float ca = (1.f - fh) * P[ha][wa] + fh * P[hb][wa];
            float cb = (1.f - fh) * P[ha][wb] + fh * P[hb][wb];
            res[k] = (1.f - fw) * ca + fw * cb;
        }
        float4 o;
        o.x = fmaf(g, res[0], xv.x);
        o.y = fmaf(g, res[1], xv.y);
        o.z = fmaf(g, res[2], xv.z);
        o.w = fmaf(g, res[3], xv.w);
        *(float4*)(op + h * 128 + wq * 4) = o;
    }
}

// ---------------------------------------------------------------------------
extern "C" void kernel_launch(void* const* d_in, const int* in_sizes, int n_in,
                              void* d_out, int out_size, void* d_ws, size_t ws_size,
                              hipStream_t stream) {
    const float* x     = (const float*)d_in[0];
    const float* Wq    = (const float*)d_in[1];
    const float* bq    = (const float*)d_in[2];
    const float* Wk    = (const float*)d_in[3];
    const float* bk    = (const float*)d_in[4];
    const float* Wv    = (const float*)d_in[5];
    const float* bv    = (const float*)d_in[6];
    const float* gamma = (const float*)d_in[7];
    float* out = (float*)d_out;

    char* wsb = (char*)d_ws;
    float*    xf   = (float*)wsb;                    // 8 MiB (dead after vgemm)
    ushort_t* Pmat = (ushort_t*)wsb;                 // 16 MiB (overlays xf)
    float*    qT   = (float*)(wsb + 16777216);
    float*    kT   = (float*)(wsb + 17039360);
    ushort_t* v    = (ushort_t*)(wsb + 17301504);
    ushort_t* outs = (ushort_t*)(wsb + 21495808);

    pool_kernel<<<8192, 256, 0, stream>>>(x, xf);
    qk_kernel<<<128, 256, 0, stream>>>(xf, Wq, bq, Wk, bk, qT, kT);
    vgemm_kernel<<<512, 256, 0, stream>>>(xf, Wv, bv, v);
    pmat_kernel<<<512, 256, 0, stream>>>(qT, kT, Pmat);
    pv_mfma_kernel<<<512, 256, 0, stream>>>(v, Pmat, outs);
    up_kernel<<<2048, 256, 0, stream>>>(outs, x, gamma, out);
}

// Round 3
// 345.986 us; speedup vs baseline: 1.2241x; 1.0021x over previous
//
#include <hip/hip_runtime.h>
#include <hip/hip_bf16.h>

// Static problem shape: B=8, C=256, CQ=8, H=W=128, scale=4, Hd=Wd=32, N=1024

typedef short bf16x8 __attribute__((ext_vector_type(8)));
typedef float f32x4 __attribute__((ext_vector_type(4)));
typedef unsigned short ushort_t;

// fp32 -> bf16 round-to-nearest-even (bit trick)
__device__ __forceinline__ ushort_t f2bf(float f) {
    union { float f; unsigned u; } x{f};
    unsigned r = x.u + 0x7FFF + ((x.u >> 16) & 1);
    return (ushort_t)(r >> 16);
}
__device__ __forceinline__ float bf2f(ushort_t u) {
    return __uint_as_float(((unsigned)u) << 16);
}

#define GLOAD_LDS16(gp, lp)                                                          \
    __builtin_amdgcn_global_load_lds((const __attribute__((address_space(1))) void*)(gp), \
                                     (__attribute__((address_space(3))) void*)(lp), 16, 0, 0)

// ---------------- ws layout (bytes) ----------------
// P    bf16 [8][1024][1024] @ 0         (16 MiB)  -- overlays xf (dead after vgemm)
// xf   f32  [8][256][1024]  @ 0         (8 MiB, phase 1 only)
// qT   f32  [8][1024][8]    @ 16777216  (256 KB)
// kT   f32  [8][1024][8]    @ 17039360  (256 KB)
// v    bf16 [8][256][1024]  @ 17301504  (4 MiB)
// outs bf16 [8][256][1024]  @ 21495808  (4 MiB)
// total 24.5 MiB (round-1 used 25.8 MiB OK)

// ---------------------------------------------------------------------------
// 1) 4x4 average pool: x[B,C,128,128] -> xf[B,C,1024] (fp32)
__global__ __launch_bounds__(256) void pool_kernel(const float* __restrict__ x,
                                                   float* __restrict__ xf) {
    int idx = blockIdx.x * 256 + threadIdx.x;      // 0..2097151
    int n = idx & 1023;
    int c = (idx >> 10) & 255;
    int b = idx >> 18;
    int hi = n >> 5, wi = n & 31;
    const float* p = x + ((size_t)(b * 256 + c) * 128 + hi * 4) * 128 + wi * 4;
    float s = 0.f;
#pragma unroll
    for (int r = 0; r < 4; ++r) {
        float4 v4 = *(const float4*)(p + r * 128);
        s += v4.x + v4.y + v4.z + v4.w;
    }
    xf[idx] = s * 0.0625f;
}

// ---------------------------------------------------------------------------
// 2) q,k projections -> qT[B][N][8], kT[B][N][8].
//    grid = 8*16 = 128 blocks; 256 thr = 64 n x 4 c-quarters; LDS reduce.
__global__ __launch_bounds__(256) void qk_kernel(const float* __restrict__ xf,
                                                 const float* __restrict__ Wq,
                                                 const float* __restrict__ bq,
                                                 const float* __restrict__ Wk,
                                                 const float* __restrict__ bk,
                                                 float* __restrict__ qT,
                                                 float* __restrict__ kT) {
    __shared__ float sW[4112];
    __shared__ float red[4352];     // [cq][64 n][17] padded
    int t = threadIdx.x;
    for (int i = t; i < 2048; i += 256) {
        sW[i] = Wq[i];
        sW[2048 + i] = Wk[i];
    }
    if (t < 8) { sW[4096 + t] = bq[t]; sW[4104 + t] = bk[t]; }
    __syncthreads();

    int b = blockIdx.x >> 4;
    int ng = blockIdx.x & 15;
    int nl = t & 63, cq = t >> 6;
    float a[16];
#pragma unroll
    for (int j = 0; j < 16; ++j) a[j] = 0.f;
    const float* xp = xf + (size_t)b * 262144 + ng * 64 + nl;
    for (int c = cq * 64; c < cq * 64 + 64; ++c) {
        float xv = xp[(size_t)c * 1024];
#pragma unroll
        for (int j = 0; j < 8; ++j) {
            a[j]     = fmaf(sW[j * 256 + c], xv, a[j]);
            a[8 + j] = fmaf(sW[2048 + j * 256 + c], xv, a[8 + j]);
        }
    }
    float* rp = &red[(cq * 64 + nl) * 17];
#pragma unroll
    for (int j = 0; j < 16; ++j) rp[j] = a[j];
    __syncthreads();
#pragma unroll
    for (int u = 0; u < 4; ++u) {
        int o = t * 4 + u;
        int n = o >> 4, j = o & 15;
        float s = red[(n) * 17 + j] + red[(64 + n) * 17 + j] +
                  red[(128 + n) * 17 + j] + red[(192 + n) * 17 + j] + sW[4096 + j];
        if (j < 8) qT[((size_t)b * 1024 + ng * 64 + n) * 8 + j] = s;
        else       kT[((size_t)b * 1024 + ng * 64 + n) * 8 + j - 8] = s;
    }
}

// ---------------------------------------------------------------------------
// 3) v projection (fp32 compute, bf16 out): v[b,o,n] = sum_c Wv[o,c]*xf[b,c,n]+bv[o]
__global__ __launch_bounds__(256) void vgemm_kernel(const float* __restrict__ xf,
                                                    const float* __restrict__ Wv,
                                                    const float* __restrict__ bv,
                                                    ushort_t* __restrict__ v) {
    int bid = blockIdx.x;
    int b = bid >> 6;
    int ot0 = ((bid >> 4) & 3) * 64;
    int nt0 = (bid & 15) * 64;
    __shared__ float WsT[32][64];  // [ck][o]
    __shared__ float Xs[32][64];   // [ck][n]
    int t = threadIdx.x;
    int to4 = (t >> 4) * 4, tn4 = (t & 15) * 4;
    float acc[4][4] = {};

    for (int c0 = 0; c0 < 256; c0 += 32) {
        {   // stage Wv tile (transposed)
            int o = t >> 2, ck0 = (t & 3) * 8;
            const float* wp = Wv + (size_t)(ot0 + o) * 256 + c0 + ck0;
            float4 aa = *(const float4*)wp;
            float4 bb = *(const float4*)(wp + 4);
            WsT[ck0 + 0][o] = aa.x;  WsT[ck0 + 1][o] = aa.y;
            WsT[ck0 + 2][o] = aa.z;  WsT[ck0 + 3][o] = aa.w;
            WsT[ck0 + 4][o] = bb.x; WsT[ck0 + 5][o] = bb.y;
            WsT[ck0 + 6][o] = bb.z; WsT[ck0 + 7][o] = bb.w;
        }
        {   // stage xf tile
            int c = t >> 3, nch = (t & 7) * 8;
            const float* xp = xf + (size_t)(b * 256 + c0 + c) * 1024 + nt0 + nch;
            *(float4*)&Xs[c][nch] = *(const float4*)xp;
            *(float4*)&Xs[c][nch + 4] = *(const float4*)(xp + 4);
        }
        __syncthreads();
#pragma unroll
        for (int ck = 0; ck < 32; ++ck) {
            float4 wv = *(float4*)&WsT[ck][to4];
            float4 xv = *(float4*)&Xs[ck][tn4];
            float wr[4] = {wv.x, wv.y, wv.z, wv.w};
            float xr[4] = {xv.x, xv.y, xv.z, xv.w};
#pragma unroll
            for (int i = 0; i < 4; ++i)
#pragma unroll
                for (int j = 0; j < 4; ++j)
                    acc[i][j] = fmaf(wr[i], xr[j], acc[i][j]);
        }
        __syncthreads();
    }
#pragma unroll
    for (int i = 0; i < 4; ++i) {
        float bias = bv[ot0 + to4 + i];
        ushort4 r;
        r.x = f2bf(acc[i][0] + bias); r.y = f2bf(acc[i][1] + bias);
        r.z = f2bf(acc[i][2] + bias); r.w = f2bf(acc[i][3] + bias);
        *(ushort4*)&v[(size_t)(b * 256 + ot0 + to4 + i) * 1024 + nt0 + tn4] = r;
    }
}

// ---------------------------------------------------------------------------
// 4) fused softmax stats + P matrix (bf16): P[b,m,n] = exp(q_m.k_n - M_m)/L_m
//    grid = 8*64 = 512 blocks; block handles 16 m rows (4 passes x 4 waves).
__global__ __launch_bounds__(256) void pmat_kernel(const float* __restrict__ qT,
                                                   const float* __restrict__ kT,
                                                   ushort_t* __restrict__ Pm) {
    __shared__ float ks[8192];     // kT[b] : 1024 x 8
    int t = threadIdx.x;
    int b = blockIdx.x >> 6;
    int mg = blockIdx.x & 63;
    const float* kp = kT + (size_t)b * 8192;
    for (int i = t * 4; i < 8192; i += 1024)
        *(float4*)&ks[i] = *(const float4*)&kp[i];
    __syncthreads();

    int w = t >> 6, ln = t & 63;
#pragma unroll 1
    for (int pass = 0; pass < 4; ++pass) {
        int m = mg * 16 + pass * 4 + w;
        const float* qp = qT + ((size_t)b * 1024 + m) * 8;
        float4 q0 = *(const float4*)qp, q1 = *(const float4*)(qp + 4);
        float s[16];
        float mx = -1e30f;
#pragma unroll
        for (int i = 0; i < 16; ++i) {
            const float* kk = &ks[(ln + i * 64) * 8];
            float4 k0 = *(const float4*)kk, k1 = *(const float4*)(kk + 4);
            float d = q0.x * k0.x + q0.y * k0.y + q0.z * k0.z + q0.w * k0.w +
                      q1.x * k1.x + q1.y * k1.y + q1.z * k1.z + q1.w * k1.w;
            s[i] = d;
            mx = fmaxf(mx, d);
        }
#pragma unroll
        for (int off = 32; off; off >>= 1) mx = fmaxf(mx, __shfl_xor(mx, off, 64));
        float sum = 0.f;
#pragma unroll
        for (int i = 0; i < 16; ++i) { s[i] = __expf(s[i] - mx); sum += s[i]; }
#pragma unroll
        for (int off = 32; off; off >>= 1) sum += __shfl_xor(sum, off, 64);
        float inv = 1.0f / sum;
        ushort_t* pp = Pm + ((size_t)b * 1024 + m) * 1024;
#pragma unroll
        for (int i = 0; i < 16; ++i) pp[ln + i * 64] = f2bf(s[i] * inv);
    }
}

// ---------------------------------------------------------------------------
// 5) PV GEMM, bf16 MFMA: outs[b,c,m] = sum_n v[b,c,n] * P[b,m,n]
//    64x64 output tile, BK=64, global_load_lds(16B) staging, m97 structure.
__global__ __launch_bounds__(256) void pv_mfma_kernel(const ushort_t* __restrict__ v,
                                                      const ushort_t* __restrict__ Pm,
                                                      ushort_t* __restrict__ outs) {
    int bid = blockIdx.x;
    int b = bid >> 6;
    int ct0 = ((bid >> 4) & 3) * 64;
    int mt0 = (bid & 15) * 64;
    __shared__ __align__(16) short vs[4096];   // [64 c][64 k] bf16, 128B rows
    __shared__ __align__(16) short ps[4096];   // [64 m][64 k] bf16
    int t = threadIdx.x;
    int w = t >> 6, ln = t & 63;
    int lrow = ln >> 3, lcol = ln & 7;         // staging: 8 rows x 128B per instr

    const char* vg = (const char*)(v + (size_t)(b * 256 + ct0) * 1024);
    const char* pg = (const char*)(Pm + (size_t)(b * 1024 + mt0) * 1024);

    f32x4 acc[4] = {};
    int fr = ln & 15, quad = ln >> 4;

    for (int n0 = 0; n0 < 1024; n0 += 64) {
        __syncthreads();   // protect prev-iter LDS reads
#pragma unroll
        for (int s = w; s < 8; s += 4) {       // segs w, w+4
            GLOAD_LDS16(vg + (size_t)(s * 8 + lrow) * 2048 + n0 * 2 + lcol * 16,
                        (char*)vs + s * 1024);
            GLOAD_LDS16(pg + (size_t)(s * 8 + lrow) * 2048 + n0 * 2 + lcol * 16,
                        (char*)ps + s * 1024);
        }
        __syncthreads();   // staged (compiler drains vmcnt before barrier)
        const short* va = vs + (w * 16 + fr) * 64;
#pragma unroll
        for (int kh = 0; kh < 2; ++kh) {
            bf16x8 af = *(const bf16x8*)(va + kh * 32 + quad * 8);
#pragma unroll
            for (int mt = 0; mt < 4; ++mt) {
                bf16x8 bfr = *(const bf16x8*)(ps + (mt * 16 + fr) * 64 + kh * 32 + quad * 8);
                acc[mt] = __builtin_amdgcn_mfma_f32_16x16x32_bf16(af, bfr, acc[mt], 0, 0, 0);
            }
        }
    }
    // epilogue: C/D layout col=lane&15 (m), row=quad*4+reg (c)
    ushort_t* og = outs + (size_t)(b * 256 + ct0 + w * 16) * 1024 + mt0;
#pragma unroll
    for (int mt = 0; mt < 4; ++mt) {
#pragma unroll
        for (int r = 0; r < 4; ++r) {
            int c = quad * 4 + r;
            og[(size_t)c * 1024 + mt * 16 + fr] = f2bf(acc[mt][r]);
        }
    }
}

// ---------------------------------------------------------------------------
// 6) bilinear 4x upsample + residual: out = gamma*up(outs) + x
__global__ __launch_bounds__(256) void up_kernel(const ushort_t* __restrict__ outs,
                                                 const float* __restrict__ x,
                                                 const float* __restrict__ gamma,
                                                 float* __restrict__ out) {
    int bc = blockIdx.x;   // 0..2047
    __shared__ float P[32][33];
    int t = threadIdx.x;
    const ushort_t* sp = outs + (size_t)bc * 1024;
    for (int i = t; i < 1024; i += 256) P[i >> 5][i & 31] = bf2f(sp[i]);
    float g = gamma[0];
    __syncthreads();

    const float* xp = x + (size_t)bc * 16384;
    float* op = out + (size_t)bc * 16384;
#pragma unroll 1
    for (int it = 0; it < 16; ++it) {
        int pix = it * 256 + t;        // float4 index 0..4095
        int h = pix >> 5;
        int wq = pix & 31;
        int hq = h >> 2, r = h & 3;
        int i0 = hq + ((r < 2) ? -1 : 0);
        float fh = (r < 2) ? (0.625f + 0.25f * r) : (0.25f * r - 0.375f);
        int ha = i0 < 0 ? 0 : i0;
        int hb = (i0 + 1) > 31 ? 31 : (i0 + 1);
        float4 xv = *(const float4*)(xp + h * 128 + wq * 4);
        float res[4];
#pragma unroll
        for (int k = 0; k < 4; ++k) {
            int j0 = wq + ((k < 2) ? -1 : 0);
            float fw = (k < 2) ? (0.625f + 0.25f * k) : (0.25f * k - 0.375f);
            int wa = j0 < 0 ? 0 : j0;
            int wb = (j0 + 1) > 31 ? 31 : (j0 + 1);
            float ca = (1.f - fh) * P[ha][wa] + fh * P[hb][wa];
            float cb = (1.f - fh) * P[ha][wb] + fh * P[hb][wb];
            res[k] = (1.f - fw) * ca + fw * cb;
        }
        float4 o;
        o.x = fmaf(g, res[0], xv.x);
        o.y = fmaf(g, res[1], xv.y);
        o.z = fmaf(g, res[2], xv.z);
        o.w = fmaf(g, res[3], xv.w);
        *(float4*)(op + h * 128 + wq * 4) = o;
    }
}

// ---------------------------------------------------------------------------
extern "C" void kernel_launch(void* const* d_in, const int* in_sizes, int n_in,
                              void* d_out, int out_size, void* d_ws, size_t ws_size,
                              hipStream_t stream) {
    const float* x     = (const float*)d_in[0];
    const float* Wq    = (const float*)d_in[1];
    const float* bq    = (const float*)d_in[2];
    const float* Wk    = (const float*)d_in[3];
    const float* bk    = (const float*)d_in[4];
    const float* Wv    = (const float*)d_in[5];
    const float* bv    = (const float*)d_in[6];
    const float* gamma = (const float*)d_in[7];
    float* out = (float*)d_out;

    char* wsb = (char*)d_ws;
    float*    xf   = (float*)wsb;                    // 8 MiB (dead after vgemm)
    ushort_t* Pmat = (ushort_t*)wsb;                 // 16 MiB (overlays xf)
    float*    qT   = (float*)(wsb + 16777216);
    float*    kT   = (float*)(wsb + 17039360);
    ushort_t* v    = (ushort_t*)(wsb + 17301504);
    ushort_t* outs = (ushort_t*)(wsb + 21495808);

    pool_kernel<<<8192, 256, 0, stream>>>(x, xf);
    qk_kernel<<<128, 256, 0, stream>>>(xf, Wq, bq, Wk, bk, qT, kT);
    vgemm_kernel<<<512, 256, 0, stream>>>(xf, Wv, bv, v);
    pmat_kernel<<<512, 256, 0, stream>>>(qT, kT, Pmat);
    pv_mfma_kernel<<<512, 256, 0, stream>>>(v, Pmat, outs);
    up_kernel<<<2048, 256, 0, stream>>>(outs, x, gamma, out);
}